// Round 8
// baseline (965.997 us; speedup 1.0000x reference)
//
#include <hip/hip_runtime.h>

#define DD 128   // feature dim
#define CHSH 14  // chunk shift: 16384 rows/chunk -> 2.1 MB fp8 slice
#define RPB 48   // rows per block (4 waves x 12)
#define RPW 12   // rows per wave

typedef unsigned int uint32;
typedef unsigned short ushort_t;
typedef __attribute__((ext_vector_type(8))) short short8;
typedef __attribute__((ext_vector_type(4))) float f32x4;
typedef __attribute__((ext_vector_type(2))) float f32x2;

__device__ __forceinline__ uint32 pack_bf16(float a, float b) {
    uint32 ua = __builtin_bit_cast(uint32, a);
    uint32 ub = __builtin_bit_cast(uint32, b);
    ua = (ua + 0x7fffu + ((ua >> 16) & 1u)) >> 16;   // RNE
    ub = (ub + 0x7fffu + ((ub >> 16) & 1u)) >> 16;
    return ua | (ub << 16);
}

// ---------------- fp8 e4m3 helpers (hw path on gfx950, sw fallback) ----------------
#if __has_builtin(__builtin_amdgcn_cvt_pk_f32_fp8) && __has_builtin(__builtin_amdgcn_cvt_pk_fp8_f32)
#define FP8_HW 1
#else
#define FP8_HW 0
#endif

#if !FP8_HW
__device__ __forceinline__ float fp8_dec1(uint32 b) {
    uint32 s = (b >> 7) & 1, e = (b >> 3) & 15, m = b & 7;
    float v = (e == 0) ? ldexpf((float)m, -9) : ldexpf((float)(8 + m), (int)e - 10);
    return s ? -v : v;
}
__device__ __forceinline__ uint32 fp8_enc1(float x) {
    uint32 u = __builtin_bit_cast(uint32, x);
    uint32 s = (u >> 31) << 7;
    float ax = fabsf(x);
    if (ax >= 448.f) return s | 0x7E;
    if (ax < 0.0009765625f) return s;   // < 2^-10 -> 0
    if (ax >= 0.015625f) {              // normal
        uint32 e = (u >> 23) & 0xFF;
        uint32 m = u & 0x7FFFFF;
        uint32 keep = m >> 20, rest = m & 0xFFFFF;
        keep += (rest > 0x80000u) || (rest == 0x80000u && (keep & 1));
        uint32 ee = e - 127 + 7;
        if (keep == 8) { keep = 0; ee += 1; }
        if (ee > 15 || (ee == 15 && keep > 6)) return s | 0x7E;
        return s | (ee << 3) | keep;
    }
    uint32 ni = (uint32)(ax * 512.f + 0.5f);
    if (ni >= 8) return s | (1u << 3);
    return s | ni;
}
#endif

template <bool WORD>
__device__ __forceinline__ f32x2 fp8x2_dec(uint32 u) {
#if FP8_HW
    return __builtin_amdgcn_cvt_pk_f32_fp8(u, WORD);
#else
    uint32 v = WORD ? (u >> 16) : u;
    f32x2 r; r.x = fp8_dec1(v & 0xff); r.y = fp8_dec1((v >> 8) & 0xff);
    return r;
#endif
}

__device__ __forceinline__ uint32 fp8x2_enc(float a, float b) {
#if FP8_HW
    return __builtin_amdgcn_cvt_pk_fp8_f32(a, b, 0, false) & 0xffffu;
#else
    return fp8_enc1(a) | (fp8_enc1(b) << 8);
#endif
}

__device__ __forceinline__ uint32 fp8x4_enc(float4 f) {
#if FP8_HW
    uint32 w = __builtin_amdgcn_cvt_pk_fp8_f32(f.x, f.y, 0, false);
    w = __builtin_amdgcn_cvt_pk_fp8_f32(f.z, f.w, w, true);
    return w;
#else
    return fp8_enc1(f.x) | (fp8_enc1(f.y) << 8) | (fp8_enc1(f.z) << 16) | (fp8_enc1(f.w) << 24);
#endif
}

// ---------------- row_ptr via binary search on sorted edge_row ----------------
__global__ __launch_bounds__(256) void k_row_ptr(const int* __restrict__ row,
                                                 int* __restrict__ rp, int n, int e) {
    int i = blockIdx.x * 256 + threadIdx.x;
    if (i > n) return;
    int lo = 0, hi = e;
    while (lo < hi) { int m = (lo + hi) >> 1; if (row[m] < i) lo = m + 1; else hi = m; }
    rp[i] = lo;
}

// ---------------- prep: feat -> fp8 (gather copy); W1,W2 -> bf16 ----------------
__global__ __launch_bounds__(256) void k_prep(const float* __restrict__ feat,
                                              uint32* __restrict__ featq,
                                              const float* __restrict__ W1,
                                              const float* __restrict__ W2,
                                              uint32* __restrict__ Wb1,
                                              uint32* __restrict__ Wb2, int n) {
    int id = blockIdx.x * 256 + threadIdx.x;
    if (id < n * (DD / 4)) {
        float4 f = ((const float4*)feat)[id];
        featq[id] = fp8x4_enc(f);
    }
    if (id < 2 * DD * DD / 4) {                    // 8192 float4 slots
        int mat = id >> 12, rem = id & 4095;
        float4 wv = ((const float4*)(mat ? W2 : W1))[rem];
        uint2 p;
        p.x = pack_bf16(wv.x, wv.y);
        p.y = pack_bf16(wv.z, wv.w);
        ((uint2*)(mat ? Wb2 : Wb1))[rem] = p;
    }
}

// ---------------- k_sort: per-row stable counting sort of edges by col-chunk ----------
// one LANE per row. Writes sorted (col, val_bits) pairs + per-row chunk starts rpc[r*8+c].
__global__ __launch_bounds__(256) void k_sort(const int* __restrict__ col,
                                              const float* __restrict__ val,
                                              const int* __restrict__ rp,
                                              int2* __restrict__ colv,
                                              int* __restrict__ rpc, int n) {
    int r = blockIdx.x * 256 + threadIdx.x;
    if (r >= n) return;
    int s = rp[r], e = rp[r + 1];
    int c0 = 0, c1 = 0, c2 = 0, c3 = 0, c4 = 0, c5 = 0;
    for (int i = s; i < e; ++i) {
        int ch = col[i] >> CHSH;
        c0 += (ch == 0); c1 += (ch == 1); c2 += (ch == 2);
        c3 += (ch == 3); c4 += (ch == 4); c5 += (ch == 5);
    }
    int o0 = s, o1 = o0 + c0, o2 = o1 + c1, o3 = o2 + c2,
        o4 = o3 + c3, o5 = o4 + c4, o6 = o5 + c5;
    int base = r * 8;
    rpc[base + 0] = o0; rpc[base + 1] = o1; rpc[base + 2] = o2; rpc[base + 3] = o3;
    rpc[base + 4] = o4; rpc[base + 5] = o5; rpc[base + 6] = o6; rpc[base + 7] = e;
    for (int i = s; i < e; ++i) {
        int cc = col[i];
        int vb = __builtin_bit_cast(int, val[i]);
        int ch = cc >> CHSH;
        int pos;
        if      (ch == 0) pos = o0++;
        else if (ch == 1) pos = o1++;
        else if (ch == 2) pos = o2++;
        else if (ch == 3) pos = o3++;
        else if (ch == 4) pos = o4++;
        else if (ch == 5) pos = o5++;
        else              pos = o6++;
        colv[pos] = make_int2(cc, vb);
    }
}

// ---------------- SpMM, chunk-outer temporal blocking ----------------
// Block = 4 waves x 12 rows. Wave owns 12 rows; acc in VGPRs (f32x2 per row, lane = 2 dims).
// Outer loop over col-chunks: all blocks march 0..nch-1 in loose lockstep -> table slice
// (2.1 MB fp8) is L2-resident while being gathered.
// PASS 1: out1 = L1x (bf16), out2 = inter (fp8); PASS 2: out1 = Linter (bf16)
template <int PASS>
__global__ __launch_bounds__(256) void k_spmm(const int2* __restrict__ colv,
                                              const ushort_t* __restrict__ tbl,
                                              const int* __restrict__ rpc,
                                              const float* __restrict__ feat,
                                              const float* __restrict__ diag,
                                              uint32* __restrict__ out1,
                                              ushort_t* __restrict__ out2,
                                              int n, int nch) {
    int t = threadIdx.x;
    int lane = t & 63, wv = t >> 6;
    int rowbase = blockIdx.x * RPB + wv * RPW;

    f32x2 acc[RPW];
#pragma unroll
    for (int rr = 0; rr < RPW; ++rr) acc[rr] = (f32x2){0.f, 0.f};

    for (int c = 0; c < nch; ++c) {
#pragma unroll
        for (int rr = 0; rr < RPW; ++rr) {
            int r = rowbase + rr;
            if (r >= n) continue;                      // wave-uniform
            int b = rpc[r * 8 + c], e2 = rpc[r * 8 + c + 1];
            f32x2 a = acc[rr];
            for (int e = b; e < e2; ++e) {
                int2 cv = colv[e];                     // wave-uniform -> s_load
                const ushort_t* p = tbl + ((size_t)cv.x << 6);
                uint32 g = p[lane];                    // 2B/lane, 128B line per edge
                float v = __builtin_bit_cast(float, cv.y);
                f32x2 d = fp8x2_dec<false>(g);
                a.x = fmaf(v, d.x, a.x);
                a.y = fmaf(v, d.y, a.y);
            }
            acc[rr] = a;
        }
    }
#pragma unroll
    for (int rr = 0; rr < RPW; ++rr) {
        int r = rowbase + rr;
        if (r >= n) continue;
        f32x2 a = acc[rr];
        if (PASS == 1) {
            float dg = diag[r];
            float2 f = ((const float2*)feat)[(size_t)r * 64 + lane];
            out1[(size_t)r * 64 + lane] = pack_bf16(fmaf(dg, f.x, a.x), fmaf(dg, f.y, a.y));
            out2[(size_t)r * 64 + lane] = (ushort_t)fp8x2_enc(a.x * f.x, a.y * f.y);
        } else {
            out1[(size_t)r * 64 + lane] = pack_bf16(a.x, a.y);
        }
    }
}

// ---------------- fused dual GEMM via MFMA: out = A@W1^T + B@W2^T + b1 + b2 ----------------
__global__ __launch_bounds__(512, 2) void k_gemm(const uint32* __restrict__ Abf,
                                                 const uint32* __restrict__ Bbf,
                                                 const uint32* __restrict__ Wb1g,
                                                 const uint32* __restrict__ Wb2g,
                                                 const float* __restrict__ b1,
                                                 const float* __restrict__ b2,
                                                 float* __restrict__ out, int n) {
    __shared__ __align__(16) char lds[65536];   // Wb1 @0, Wb2 @32768 (32 KB each)
    int t = threadIdx.x;
    {
        const uint2* s1 = (const uint2*)Wb1g;
        const uint2* s2 = (const uint2*)Wb2g;
#pragma unroll
        for (int u = 0; u < 16; ++u) {
            int id = u * 512 + t;                  // 0..8191 uint2 slots
            int j = id >> 5, kq = id & 31;
            int dst = j * 256 + ((kq * 8) ^ ((j & 7) << 4));
            *(uint2*)(lds + dst) = s1[id];
            *(uint2*)(lds + 32768 + dst) = s2[id];
        }
    }
    __syncthreads();
    int lane = t & 63, w = t >> 6;
    int g = lane >> 4;                             // k-chunk group 0..3
    int rowbase = blockIdx.x * 256 + w * 32;
    int rr = rowbase + (lane & 15);
    int r0 = min(rr, n - 1);
    int r1 = min(rr + 16, n - 1);
    const uint4* A4 = (const uint4*)Abf;           // 16 uint4 per row
    const uint4* B4 = (const uint4*)Bbf;

    f32x4 acc[2][8];
#pragma unroll
    for (int mt = 0; mt < 2; ++mt)
#pragma unroll
        for (int jt = 0; jt < 8; ++jt) acc[mt][jt] = (f32x4){0.f, 0.f, 0.f, 0.f};

    uint4 a0 = A4[(size_t)r0 * 16 + g], a1 = A4[(size_t)r1 * 16 + g];
    uint4 c0 = B4[(size_t)r0 * 16 + g], c1 = B4[(size_t)r1 * 16 + g];
#pragma unroll
    for (int kc = 0; kc < 4; ++kc) {
        uint4 na0, na1, nc0, nc1;
        if (kc < 3) {
            na0 = A4[(size_t)r0 * 16 + (kc + 1) * 4 + g];
            na1 = A4[(size_t)r1 * 16 + (kc + 1) * 4 + g];
            nc0 = B4[(size_t)r0 * 16 + (kc + 1) * 4 + g];
            nc1 = B4[(size_t)r1 * 16 + (kc + 1) * 4 + g];
        }
        short8 fa0 = __builtin_bit_cast(short8, a0);
        short8 fa1 = __builtin_bit_cast(short8, a1);
        short8 fc0 = __builtin_bit_cast(short8, c0);
        short8 fc1 = __builtin_bit_cast(short8, c1);
        int kbase = kc * 64 + g * 16;
#pragma unroll
        for (int jt = 0; jt < 8; ++jt) {
            int j = jt * 16 + (lane & 15);
            int off = j * 256 + (kbase ^ ((j & 7) << 4));
            short8 w1 = *(const short8*)(lds + off);
            short8 w2 = *(const short8*)(lds + 32768 + off);
            acc[0][jt] = __builtin_amdgcn_mfma_f32_16x16x32_bf16(fa0, w1, acc[0][jt], 0, 0, 0);
            acc[0][jt] = __builtin_amdgcn_mfma_f32_16x16x32_bf16(fc0, w2, acc[0][jt], 0, 0, 0);
            acc[1][jt] = __builtin_amdgcn_mfma_f32_16x16x32_bf16(fa1, w1, acc[1][jt], 0, 0, 0);
            acc[1][jt] = __builtin_amdgcn_mfma_f32_16x16x32_bf16(fc1, w2, acc[1][jt], 0, 0, 0);
        }
        a0 = na0; a1 = na1; c0 = nc0; c1 = nc1;
    }
    float bsum[8];
#pragma unroll
    for (int jt = 0; jt < 8; ++jt) {
        int cj = jt * 16 + (lane & 15);
        bsum[jt] = b1[cj] + b2[cj];
    }
#pragma unroll
    for (int mt = 0; mt < 2; ++mt) {
#pragma unroll
        for (int i = 0; i < 4; ++i) {
            int r = rowbase + mt * 16 + g * 4 + i;
            if (r < n) {
                float* orow = out + (size_t)r * DD;
#pragma unroll
                for (int jt = 0; jt < 8; ++jt)
                    orow[jt * 16 + (lane & 15)] = acc[mt][jt][i] + bsum[jt];
            }
        }
    }
}

extern "C" void kernel_launch(void* const* d_in, const int* in_sizes, int n_in,
                              void* d_out, int out_size, void* d_ws, size_t ws_size,
                              hipStream_t stream) {
    const int*   edge_row = (const int*)d_in[0];
    const int*   edge_col = (const int*)d_in[1];
    const float* edge_val = (const float*)d_in[2];
    const float* diag     = (const float*)d_in[3];
    const float* feat     = (const float*)d_in[4];
    const float* W1       = (const float*)d_in[5];
    const float* b1       = (const float*)d_in[6];
    const float* W2       = (const float*)d_in[7];
    const float* b2       = (const float*)d_in[8];
    float* out = (float*)d_out;

    const int E = in_sizes[0];
    const int N = in_sizes[3];
    const int NCH = (N + (1 << CHSH) - 1) >> CHSH;   // 7 for N=100000

    // workspace layout
    char* ws = (char*)d_ws;
    size_t off = 0;
    int* rp            = (int*)(ws + off);      off += (((size_t)(N + 1) * 4) + 255) & ~(size_t)255;
    int* rpc           = (int*)(ws + off);      off += (size_t)N * 8 * 4;
    int2* colv         = (int2*)(ws + off);     off += (size_t)E * 8;
    uint32* featq      = (uint32*)(ws + off);   off += (size_t)N * (DD / 4) * 4;   // fp8 x
    uint32* interq     = (uint32*)(ws + off);   off += (size_t)N * (DD / 4) * 4;   // fp8 inter
    uint32* L1xbf      = (uint32*)(ws + off);   off += (size_t)N * (DD / 2) * 4;
    uint32* Linterbf   = (uint32*)(ws + off);   off += (size_t)N * (DD / 2) * 4;
    uint32* Wb1g       = (uint32*)(ws + off);   off += (size_t)DD * (DD / 2) * 4;
    uint32* Wb2g       = (uint32*)(ws + off);   off += (size_t)DD * (DD / 2) * 4;
    (void)ws_size; (void)n_in; (void)out_size;

    // 1. row_ptr
    k_row_ptr<<<(N + 1 + 255) / 256, 256, 0, stream>>>(edge_row, rp, N, E);
    // 2. prep: feat -> fp8, W -> bf16
    {
        int work = N * (DD / 4);
        if (work < 2 * DD * DD / 4) work = 2 * DD * DD / 4;
        k_prep<<<(work + 255) / 256, 256, 0, stream>>>(feat, featq, W1, W2, Wb1g, Wb2g, N);
    }
    // 3. sort edges by col-chunk within each row
    k_sort<<<(N + 255) / 256, 256, 0, stream>>>(edge_col, edge_val, rp, colv, rpc, N);
    const int spmm_blocks = (N + RPB - 1) / RPB;
    // 4. SpMM pass 1: L1x (bf16), inter (fp8)
    k_spmm<1><<<spmm_blocks, 256, 0, stream>>>(colv, (const ushort_t*)featq, rpc,
                                               feat, diag, L1xbf, (ushort_t*)interq, N, NCH);
    // 5. SpMM pass 2: Linter (bf16)
    k_spmm<2><<<spmm_blocks, 256, 0, stream>>>(colv, (const ushort_t*)interq, rpc,
                                               nullptr, nullptr, Linterbf, nullptr, N, NCH);
    // 6. fused dual GEMM + bias (MFMA)
    k_gemm<<<(N + 255) / 256, 512, 0, stream>>>(L1xbf, Linterbf, Wb1g, Wb2g, b1, b2, out, N);
}

// Round 9
// 396.018 us; speedup vs baseline: 2.4393x; 2.4393x over previous
//
#include <hip/hip_runtime.h>

#define DD 128   // feature dim
#define UN 16    // edge unroll (lines in flight per wave)

typedef unsigned int uint32;
typedef unsigned short ushort_t;
typedef __attribute__((ext_vector_type(8))) short short8;
typedef __attribute__((ext_vector_type(4))) float f32x4;
typedef __attribute__((ext_vector_type(2))) float f32x2;

__device__ __forceinline__ uint32 pack_bf16(float a, float b) {
    uint32 ua = __builtin_bit_cast(uint32, a);
    uint32 ub = __builtin_bit_cast(uint32, b);
    ua = (ua + 0x7fffu + ((ua >> 16) & 1u)) >> 16;   // RNE
    ub = (ub + 0x7fffu + ((ub >> 16) & 1u)) >> 16;
    return ua | (ub << 16);
}

// ---------------- fp8 e4m3 helpers (hw path on gfx950, sw fallback) ----------------
#if __has_builtin(__builtin_amdgcn_cvt_pk_f32_fp8) && __has_builtin(__builtin_amdgcn_cvt_pk_fp8_f32)
#define FP8_HW 1
#else
#define FP8_HW 0
#endif

#if !FP8_HW
__device__ __forceinline__ float fp8_dec1(uint32 b) {
    uint32 s = (b >> 7) & 1, e = (b >> 3) & 15, m = b & 7;
    float v = (e == 0) ? ldexpf((float)m, -9) : ldexpf((float)(8 + m), (int)e - 10);
    return s ? -v : v;
}
__device__ __forceinline__ uint32 fp8_enc1(float x) {
    uint32 u = __builtin_bit_cast(uint32, x);
    uint32 s = (u >> 31) << 7;
    float ax = fabsf(x);
    if (ax >= 448.f) return s | 0x7E;
    if (ax < 0.0009765625f) return s;   // < 2^-10 -> 0
    if (ax >= 0.015625f) {              // normal
        uint32 e = (u >> 23) & 0xFF;
        uint32 m = u & 0x7FFFFF;
        uint32 keep = m >> 20, rest = m & 0xFFFFF;
        keep += (rest > 0x80000u) || (rest == 0x80000u && (keep & 1));
        uint32 ee = e - 127 + 7;
        if (keep == 8) { keep = 0; ee += 1; }
        if (ee > 15 || (ee == 15 && keep > 6)) return s | 0x7E;
        return s | (ee << 3) | keep;
    }
    uint32 ni = (uint32)(ax * 512.f + 0.5f);
    if (ni >= 8) return s | (1u << 3);
    return s | ni;
}
#endif

template <bool WORD>
__device__ __forceinline__ f32x2 fp8x2_dec(uint32 u) {
#if FP8_HW
    return __builtin_amdgcn_cvt_pk_f32_fp8(u, WORD);
#else
    uint32 v = WORD ? (u >> 16) : u;
    f32x2 r; r.x = fp8_dec1(v & 0xff); r.y = fp8_dec1((v >> 8) & 0xff);
    return r;
#endif
}

__device__ __forceinline__ uint32 fp8x2_enc(float a, float b) {
#if FP8_HW
    return __builtin_amdgcn_cvt_pk_fp8_f32(a, b, 0, false) & 0xffffu;
#else
    return fp8_enc1(a) | (fp8_enc1(b) << 8);
#endif
}

__device__ __forceinline__ uint32 fp8x4_enc(float4 f) {
#if FP8_HW
    uint32 w = __builtin_amdgcn_cvt_pk_fp8_f32(f.x, f.y, 0, false);
    w = __builtin_amdgcn_cvt_pk_fp8_f32(f.z, f.w, w, true);
    return w;
#else
    return fp8_enc1(f.x) | (fp8_enc1(f.y) << 8) | (fp8_enc1(f.z) << 16) | (fp8_enc1(f.w) << 24);
#endif
}

// ---------------- row_ptr via binary search on sorted edge_row ----------------
__global__ __launch_bounds__(256) void k_row_ptr(const int* __restrict__ row,
                                                 int* __restrict__ rp, int n, int e) {
    int i = blockIdx.x * 256 + threadIdx.x;
    if (i > n) return;
    int lo = 0, hi = e;
    while (lo < hi) { int m = (lo + hi) >> 1; if (row[m] < i) lo = m + 1; else hi = m; }
    rp[i] = lo;
}

// ---------------- prep: feat -> fp8 (gather copy); W1,W2 -> bf16 ----------------
__global__ __launch_bounds__(256) void k_prep(const float* __restrict__ feat,
                                              uint32* __restrict__ featq,
                                              const float* __restrict__ W1,
                                              const float* __restrict__ W2,
                                              uint32* __restrict__ Wb1,
                                              uint32* __restrict__ Wb2, int n) {
    int id = blockIdx.x * 256 + threadIdx.x;
    if (id < n * (DD / 4)) {
        float4 f = ((const float4*)feat)[id];
        featq[id] = fp8x4_enc(f);
    }
    if (id < 2 * DD * DD / 4) {                    // 8192 float4 slots
        int mat = id >> 12, rem = id & 4095;
        float4 wv = ((const float4*)(mat ? W2 : W1))[rem];
        uint2 p;
        p.x = pack_bf16(wv.x, wv.y);
        p.y = pack_bf16(wv.z, wv.w);
        ((uint2*)(mat ? Wb2 : Wb1))[rem] = p;
    }
}

// ---------------- SpMM: one wave per row, lane owns an fp8 pair (2B gather) ----------------
// Predicated unroll-UN: edge index clamped (scalar), val zeroed for pad slots.
// PASS 1: out1 = L1x (bf16), out2 = inter (fp8) ; PASS 2: out1 = Linter (bf16)
template <int PASS>
__global__ __launch_bounds__(256) void k_spmm(const int* __restrict__ col,
                                              const float* __restrict__ val,
                                              const ushort_t* __restrict__ xq,
                                              const int* __restrict__ rp,
                                              const float* __restrict__ feat,
                                              const float* __restrict__ diag,
                                              uint32* __restrict__ out1,
                                              ushort_t* __restrict__ out2, int n) {
    int lane = threadIdx.x & 63;
    int row = blockIdx.x * 4 + (threadIdx.x >> 6);
    if (row >= n) return;
    row = __builtin_amdgcn_readfirstlane(row);  // wave-uniform -> scalar loads
    int s = rp[row], eend = rp[row + 1];
    float ax = 0.f, ay = 0.f;

    for (int e = s; e < eend; e += UN) {
        uint32 g[UN]; float vv[UN];
#pragma unroll
        for (int u = 0; u < UN; ++u) {
            int ee = e + u;
            int ec = min(ee, eend - 1);            // scalar clamp
            int c = col[ec];                       // s_load
            vv[u] = (ee < eend) ? val[ec] : 0.f;   // s_load + s_cselect
            g[u] = xq[((size_t)c << 6) + lane];    // 2B/lane, one 128B line per edge
        }
#pragma unroll
        for (int u = 0; u < UN; ++u) {
            f32x2 d = fp8x2_dec<false>(g[u]);
            ax = fmaf(vv[u], d.x, ax);
            ay = fmaf(vv[u], d.y, ay);
        }
    }
    if (PASS == 1) {
        float dg = diag[row];
        float2 f = ((const float2*)feat)[(size_t)row * 64 + lane];
        out1[(size_t)row * 64 + lane] = pack_bf16(fmaf(dg, f.x, ax), fmaf(dg, f.y, ay));
        out2[(size_t)row * 64 + lane] = (ushort_t)fp8x2_enc(ax * f.x, ay * f.y);
    } else {
        out1[(size_t)row * 64 + lane] = pack_bf16(ax, ay);
    }
}

// ---------------- fused dual GEMM via MFMA: out = A@W1^T + B@W2^T + b1 + b2 ----------------
__global__ __launch_bounds__(512, 2) void k_gemm(const uint32* __restrict__ Abf,
                                                 const uint32* __restrict__ Bbf,
                                                 const uint32* __restrict__ Wb1g,
                                                 const uint32* __restrict__ Wb2g,
                                                 const float* __restrict__ b1,
                                                 const float* __restrict__ b2,
                                                 float* __restrict__ out, int n) {
    __shared__ __align__(16) char lds[65536];   // Wb1 @0, Wb2 @32768 (32 KB each)
    int t = threadIdx.x;
    {
        const uint2* s1 = (const uint2*)Wb1g;
        const uint2* s2 = (const uint2*)Wb2g;
#pragma unroll
        for (int u = 0; u < 16; ++u) {
            int id = u * 512 + t;                  // 0..8191 uint2 slots
            int j = id >> 5, kq = id & 31;
            int dst = j * 256 + ((kq * 8) ^ ((j & 7) << 4));
            *(uint2*)(lds + dst) = s1[id];
            *(uint2*)(lds + 32768 + dst) = s2[id];
        }
    }
    __syncthreads();
    int lane = t & 63, w = t >> 6;
    int g = lane >> 4;                             // k-chunk group 0..3
    int rowbase = blockIdx.x * 256 + w * 32;
    int rr = rowbase + (lane & 15);
    int r0 = min(rr, n - 1);
    int r1 = min(rr + 16, n - 1);
    const uint4* A4 = (const uint4*)Abf;           // 16 uint4 per row
    const uint4* B4 = (const uint4*)Bbf;

    f32x4 acc[2][8];
#pragma unroll
    for (int mt = 0; mt < 2; ++mt)
#pragma unroll
        for (int jt = 0; jt < 8; ++jt) acc[mt][jt] = (f32x4){0.f, 0.f, 0.f, 0.f};

    uint4 a0 = A4[(size_t)r0 * 16 + g], a1 = A4[(size_t)r1 * 16 + g];
    uint4 c0 = B4[(size_t)r0 * 16 + g], c1 = B4[(size_t)r1 * 16 + g];
#pragma unroll
    for (int kc = 0; kc < 4; ++kc) {
        uint4 na0, na1, nc0, nc1;
        if (kc < 3) {
            na0 = A4[(size_t)r0 * 16 + (kc + 1) * 4 + g];
            na1 = A4[(size_t)r1 * 16 + (kc + 1) * 4 + g];
            nc0 = B4[(size_t)r0 * 16 + (kc + 1) * 4 + g];
            nc1 = B4[(size_t)r1 * 16 + (kc + 1) * 4 + g];
        }
        short8 fa0 = __builtin_bit_cast(short8, a0);
        short8 fa1 = __builtin_bit_cast(short8, a1);
        short8 fc0 = __builtin_bit_cast(short8, c0);
        short8 fc1 = __builtin_bit_cast(short8, c1);
        int kbase = kc * 64 + g * 16;
#pragma unroll
        for (int jt = 0; jt < 8; ++jt) {
            int j = jt * 16 + (lane & 15);
            int off = j * 256 + (kbase ^ ((j & 7) << 4));
            short8 w1 = *(const short8*)(lds + off);
            short8 w2 = *(const short8*)(lds + 32768 + off);
            acc[0][jt] = __builtin_amdgcn_mfma_f32_16x16x32_bf16(fa0, w1, acc[0][jt], 0, 0, 0);
            acc[0][jt] = __builtin_amdgcn_mfma_f32_16x16x32_bf16(fc0, w2, acc[0][jt], 0, 0, 0);
            acc[1][jt] = __builtin_amdgcn_mfma_f32_16x16x32_bf16(fa1, w1, acc[1][jt], 0, 0, 0);
            acc[1][jt] = __builtin_amdgcn_mfma_f32_16x16x32_bf16(fc1, w2, acc[1][jt], 0, 0, 0);
        }
        a0 = na0; a1 = na1; c0 = nc0; c1 = nc1;
    }
    float bsum[8];
#pragma unroll
    for (int jt = 0; jt < 8; ++jt) {
        int cj = jt * 16 + (lane & 15);
        bsum[jt] = b1[cj] + b2[cj];
    }
#pragma unroll
    for (int mt = 0; mt < 2; ++mt) {
#pragma unroll
        for (int i = 0; i < 4; ++i) {
            int r = rowbase + mt * 16 + g * 4 + i;
            if (r < n) {
                float* orow = out + (size_t)r * DD;
#pragma unroll
                for (int jt = 0; jt < 8; ++jt)
                    orow[jt * 16 + (lane & 15)] = acc[mt][jt][i] + bsum[jt];
            }
        }
    }
}

extern "C" void kernel_launch(void* const* d_in, const int* in_sizes, int n_in,
                              void* d_out, int out_size, void* d_ws, size_t ws_size,
                              hipStream_t stream) {
    const int*   edge_row = (const int*)d_in[0];
    const int*   edge_col = (const int*)d_in[1];
    const float* edge_val = (const float*)d_in[2];
    const float* diag     = (const float*)d_in[3];
    const float* feat     = (const float*)d_in[4];
    const float* W1       = (const float*)d_in[5];
    const float* b1       = (const float*)d_in[6];
    const float* W2       = (const float*)d_in[7];
    const float* b2       = (const float*)d_in[8];
    float* out = (float*)d_out;

    const int E = in_sizes[0];
    const int N = in_sizes[3];

    // workspace layout
    char* ws = (char*)d_ws;
    size_t off = 0;
    int* rp            = (int*)(ws + off);      off += (((size_t)(N + 1) * 4) + 255) & ~(size_t)255;
    uint32* featq      = (uint32*)(ws + off);   off += (size_t)N * (DD / 4) * 4;   // fp8 x
    uint32* interq     = (uint32*)(ws + off);   off += (size_t)N * (DD / 4) * 4;   // fp8 inter
    uint32* L1xbf      = (uint32*)(ws + off);   off += (size_t)N * (DD / 2) * 4;
    uint32* Linterbf   = (uint32*)(ws + off);   off += (size_t)N * (DD / 2) * 4;
    uint32* Wb1g       = (uint32*)(ws + off);   off += (size_t)DD * (DD / 2) * 4;
    uint32* Wb2g       = (uint32*)(ws + off);   off += (size_t)DD * (DD / 2) * 4;
    (void)ws_size; (void)n_in; (void)out_size;

    // 1. row_ptr
    k_row_ptr<<<(N + 1 + 255) / 256, 256, 0, stream>>>(edge_row, rp, N, E);
    // 2. prep: feat -> fp8, W -> bf16
    {
        int work = N * (DD / 4);
        if (work < 2 * DD * DD / 4) work = 2 * DD * DD / 4;
        k_prep<<<(work + 255) / 256, 256, 0, stream>>>(feat, featq, W1, W2, Wb1g, Wb2g, N);
    }
    // 3. SpMM pass 1: L1x (bf16), inter (fp8)
    k_spmm<1><<<(N + 3) / 4, 256, 0, stream>>>(edge_col, edge_val, (const ushort_t*)featq, rp,
                                               feat, diag, L1xbf, (ushort_t*)interq, N);
    // 4. SpMM pass 2: Linter (bf16)
    k_spmm<2><<<(N + 3) / 4, 256, 0, stream>>>(edge_col, edge_val, (const ushort_t*)interq, rp,
                                               nullptr, nullptr, Linterbf, nullptr, N);
    // 5. fused dual GEMM + bias (MFMA)
    k_gemm<<<(N + 255) / 256, 512, 0, stream>>>(L1xbf, Linterbf, Wb1g, Wb2g, b1, b2, out, N);
}

// Round 10
// 167.995 us; speedup vs baseline: 5.7502x; 2.3573x over previous
//
#include <hip/hip_runtime.h>

#define DD 128   // feature dim

typedef unsigned int uint32;
typedef unsigned short ushort_t;
typedef __attribute__((ext_vector_type(8))) short short8;
typedef __attribute__((ext_vector_type(4))) float f32x4;
typedef __attribute__((ext_vector_type(2))) float f32x2;

__device__ __forceinline__ uint32 pack_bf16(float a, float b) {
    uint32 ua = __builtin_bit_cast(uint32, a);
    uint32 ub = __builtin_bit_cast(uint32, b);
    ua = (ua + 0x7fffu + ((ua >> 16) & 1u)) >> 16;   // RNE
    ub = (ub + 0x7fffu + ((ub >> 16) & 1u)) >> 16;
    return ua | (ub << 16);
}

// ---------------- fp8 e4m3 helpers (hw path on gfx950, sw fallback) ----------------
#if __has_builtin(__builtin_amdgcn_cvt_pk_f32_fp8) && __has_builtin(__builtin_amdgcn_cvt_pk_fp8_f32)
#define FP8_HW 1
#else
#define FP8_HW 0
#endif

#if !FP8_HW
__device__ __forceinline__ float fp8_dec1(uint32 b) {
    uint32 s = (b >> 7) & 1, e = (b >> 3) & 15, m = b & 7;
    float v = (e == 0) ? ldexpf((float)m, -9) : ldexpf((float)(8 + m), (int)e - 10);
    return s ? -v : v;
}
__device__ __forceinline__ uint32 fp8_enc1(float x) {
    uint32 u = __builtin_bit_cast(uint32, x);
    uint32 s = (u >> 31) << 7;
    float ax = fabsf(x);
    if (ax >= 448.f) return s | 0x7E;
    if (ax < 0.0009765625f) return s;   // < 2^-10 -> 0
    if (ax >= 0.015625f) {              // normal
        uint32 e = (u >> 23) & 0xFF;
        uint32 m = u & 0x7FFFFF;
        uint32 keep = m >> 20, rest = m & 0xFFFFF;
        keep += (rest > 0x80000u) || (rest == 0x80000u && (keep & 1));
        uint32 ee = e - 127 + 7;
        if (keep == 8) { keep = 0; ee += 1; }
        if (ee > 15 || (ee == 15 && keep > 6)) return s | 0x7E;
        return s | (ee << 3) | keep;
    }
    uint32 ni = (uint32)(ax * 512.f + 0.5f);
    if (ni >= 8) return s | (1u << 3);
    return s | ni;
}
#endif

template <bool WORD>
__device__ __forceinline__ f32x2 fp8x2_dec(uint32 u) {
#if FP8_HW
    return __builtin_amdgcn_cvt_pk_f32_fp8(u, WORD);
#else
    uint32 v = WORD ? (u >> 16) : u;
    f32x2 r; r.x = fp8_dec1(v & 0xff); r.y = fp8_dec1((v >> 8) & 0xff);
    return r;
#endif
}

__device__ __forceinline__ uint32 fp8x2_enc(float a, float b) {
#if FP8_HW
    return __builtin_amdgcn_cvt_pk_fp8_f32(a, b, 0, false) & 0xffffu;
#else
    return fp8_enc1(a) | (fp8_enc1(b) << 8);
#endif
}

__device__ __forceinline__ uint32 fp8x4_enc(float4 f) {
#if FP8_HW
    uint32 w = __builtin_amdgcn_cvt_pk_fp8_f32(f.x, f.y, 0, false);
    w = __builtin_amdgcn_cvt_pk_fp8_f32(f.z, f.w, w, true);
    return w;
#else
    return fp8_enc1(f.x) | (fp8_enc1(f.y) << 8) | (fp8_enc1(f.z) << 16) | (fp8_enc1(f.w) << 24);
#endif
}

// ---------------- row_ptr via binary search on sorted edge_row ----------------
__global__ __launch_bounds__(256) void k_row_ptr(const int* __restrict__ row,
                                                 int* __restrict__ rp, int n, int e) {
    int i = blockIdx.x * 256 + threadIdx.x;
    if (i > n) return;
    int lo = 0, hi = e;
    while (lo < hi) { int m = (lo + hi) >> 1; if (row[m] < i) lo = m + 1; else hi = m; }
    rp[i] = lo;
}

// ---------------- prep: feat -> fp8 (gather copy); W1,W2 -> bf16 ----------------
__global__ __launch_bounds__(256) void k_prep(const float* __restrict__ feat,
                                              uint32* __restrict__ featq,
                                              const float* __restrict__ W1,
                                              const float* __restrict__ W2,
                                              uint32* __restrict__ Wb1,
                                              uint32* __restrict__ Wb2, int n) {
    int id = blockIdx.x * 256 + threadIdx.x;
    if (id < n * (DD / 4)) {
        float4 f = ((const float4*)feat)[id];
        featq[id] = fp8x4_enc(f);
    }
    if (id < 2 * DD * DD / 4) {                    // 8192 float4 slots
        int mat = id >> 12, rem = id & 4095;
        float4 wv = ((const float4*)(mat ? W2 : W1))[rem];
        uint2 p;
        p.x = pack_bf16(wv.x, wv.y);
        p.y = pack_bf16(wv.z, wv.w);
        ((uint2*)(mat ? Wb2 : Wb1))[rem] = p;
    }
}

// ---------------- SpMM: one wave per row, lane owns an fp8 pair (2B gather) ----------------
// Guard-based contiguous batches (16/8/4) -> wide s_load of col/val; scalar tail <=3 edges.
// PASS 1: out1 = L1x (bf16), out2 = inter (fp8) ; PASS 2: out1 = Linter (bf16)
template <int PASS>
__global__ __launch_bounds__(256) void k_spmm(const int* __restrict__ col,
                                              const float* __restrict__ val,
                                              const ushort_t* __restrict__ xq,
                                              const int* __restrict__ rp,
                                              const float* __restrict__ feat,
                                              const float* __restrict__ diag,
                                              uint32* __restrict__ out1,
                                              ushort_t* __restrict__ out2, int n) {
    int lane = threadIdx.x & 63;
    int row = blockIdx.x * 4 + (threadIdx.x >> 6);
    if (row >= n) return;
    row = __builtin_amdgcn_readfirstlane(row);  // wave-uniform -> scalar loads
    int s = rp[row], eend = rp[row + 1];
    float ax = 0.f, ay = 0.f;
    int e = s;

#define SPMM_BATCH(UNN)                                                        \
    {                                                                          \
        int c[UNN]; float vv[UNN]; uint32 g[UNN];                              \
        _Pragma("unroll")                                                      \
        for (int u = 0; u < UNN; ++u) { c[u] = col[e + u]; vv[u] = val[e + u]; } \
        _Pragma("unroll")                                                      \
        for (int u = 0; u < UNN; ++u) { g[u] = xq[((size_t)c[u] << 6) + lane]; } \
        _Pragma("unroll")                                                      \
        for (int u = 0; u < UNN; ++u) {                                        \
            f32x2 d = fp8x2_dec<false>(g[u]);                                  \
            ax = fmaf(vv[u], d.x, ax);                                         \
            ay = fmaf(vv[u], d.y, ay);                                         \
        }                                                                      \
    }

    for (; e + 16 <= eend; e += 16) SPMM_BATCH(16)
    if (e + 8 <= eend) { SPMM_BATCH(8) e += 8; }
    if (e + 4 <= eend) { SPMM_BATCH(4) e += 4; }
    for (; e < eend; ++e) {
        int c = col[e]; float v = val[e];
        uint32 g = xq[((size_t)c << 6) + lane];
        f32x2 d = fp8x2_dec<false>(g);
        ax = fmaf(v, d.x, ax);
        ay = fmaf(v, d.y, ay);
    }
#undef SPMM_BATCH

    if (PASS == 1) {
        float dg = diag[row];
        float2 f = ((const float2*)feat)[(size_t)row * 64 + lane];
        out1[(size_t)row * 64 + lane] = pack_bf16(fmaf(dg, f.x, ax), fmaf(dg, f.y, ay));
        out2[(size_t)row * 64 + lane] = (ushort_t)fp8x2_enc(ax * f.x, ay * f.y);
    } else {
        out1[(size_t)row * 64 + lane] = pack_bf16(ax, ay);
    }
}

// ---------------- fused dual GEMM via MFMA: out = A@W1^T + B@W2^T + b1 + b2 ----------------
__global__ __launch_bounds__(512, 2) void k_gemm(const uint32* __restrict__ Abf,
                                                 const uint32* __restrict__ Bbf,
                                                 const uint32* __restrict__ Wb1g,
                                                 const uint32* __restrict__ Wb2g,
                                                 const float* __restrict__ b1,
                                                 const float* __restrict__ b2,
                                                 float* __restrict__ out, int n) {
    __shared__ __align__(16) char lds[65536];   // Wb1 @0, Wb2 @32768 (32 KB each)
    int t = threadIdx.x;
    {
        const uint2* s1 = (const uint2*)Wb1g;
        const uint2* s2 = (const uint2*)Wb2g;
#pragma unroll
        for (int u = 0; u < 16; ++u) {
            int id = u * 512 + t;                  // 0..8191 uint2 slots
            int j = id >> 5, kq = id & 31;
            int dst = j * 256 + ((kq * 8) ^ ((j & 7) << 4));
            *(uint2*)(lds + dst) = s1[id];
            *(uint2*)(lds + 32768 + dst) = s2[id];
        }
    }
    __syncthreads();
    int lane = t & 63, w = t >> 6;
    int g = lane >> 4;                             // k-chunk group 0..3
    int rowbase = blockIdx.x * 256 + w * 32;
    int rr = rowbase + (lane & 15);
    int r0 = min(rr, n - 1);
    int r1 = min(rr + 16, n - 1);
    const uint4* A4 = (const uint4*)Abf;           // 16 uint4 per row
    const uint4* B4 = (const uint4*)Bbf;

    f32x4 acc[2][8];
#pragma unroll
    for (int mt = 0; mt < 2; ++mt)
#pragma unroll
        for (int jt = 0; jt < 8; ++jt) acc[mt][jt] = (f32x4){0.f, 0.f, 0.f, 0.f};

    uint4 a0 = A4[(size_t)r0 * 16 + g], a1 = A4[(size_t)r1 * 16 + g];
    uint4 c0 = B4[(size_t)r0 * 16 + g], c1 = B4[(size_t)r1 * 16 + g];
#pragma unroll
    for (int kc = 0; kc < 4; ++kc) {
        uint4 na0, na1, nc0, nc1;
        if (kc < 3) {
            na0 = A4[(size_t)r0 * 16 + (kc + 1) * 4 + g];
            na1 = A4[(size_t)r1 * 16 + (kc + 1) * 4 + g];
            nc0 = B4[(size_t)r0 * 16 + (kc + 1) * 4 + g];
            nc1 = B4[(size_t)r1 * 16 + (kc + 1) * 4 + g];
        }
        short8 fa0 = __builtin_bit_cast(short8, a0);
        short8 fa1 = __builtin_bit_cast(short8, a1);
        short8 fc0 = __builtin_bit_cast(short8, c0);
        short8 fc1 = __builtin_bit_cast(short8, c1);
        int kbase = kc * 64 + g * 16;
#pragma unroll
        for (int jt = 0; jt < 8; ++jt) {
            int j = jt * 16 + (lane & 15);
            int off = j * 256 + (kbase ^ ((j & 7) << 4));
            short8 w1 = *(const short8*)(lds + off);
            short8 w2 = *(const short8*)(lds + 32768 + off);
            acc[0][jt] = __builtin_amdgcn_mfma_f32_16x16x32_bf16(fa0, w1, acc[0][jt], 0, 0, 0);
            acc[0][jt] = __builtin_amdgcn_mfma_f32_16x16x32_bf16(fc0, w2, acc[0][jt], 0, 0, 0);
            acc[1][jt] = __builtin_amdgcn_mfma_f32_16x16x32_bf16(fa1, w1, acc[1][jt], 0, 0, 0);
            acc[1][jt] = __builtin_amdgcn_mfma_f32_16x16x32_bf16(fc1, w2, acc[1][jt], 0, 0, 0);
        }
        a0 = na0; a1 = na1; c0 = nc0; c1 = nc1;
    }
    float bsum[8];
#pragma unroll
    for (int jt = 0; jt < 8; ++jt) {
        int cj = jt * 16 + (lane & 15);
        bsum[jt] = b1[cj] + b2[cj];
    }
#pragma unroll
    for (int mt = 0; mt < 2; ++mt) {
#pragma unroll
        for (int i = 0; i < 4; ++i) {
            int r = rowbase + mt * 16 + g * 4 + i;
            if (r < n) {
                float* orow = out + (size_t)r * DD;
#pragma unroll
                for (int jt = 0; jt < 8; ++jt)
                    orow[jt * 16 + (lane & 15)] = acc[mt][jt][i] + bsum[jt];
            }
        }
    }
}

extern "C" void kernel_launch(void* const* d_in, const int* in_sizes, int n_in,
                              void* d_out, int out_size, void* d_ws, size_t ws_size,
                              hipStream_t stream) {
    const int*   edge_row = (const int*)d_in[0];
    const int*   edge_col = (const int*)d_in[1];
    const float* edge_val = (const float*)d_in[2];
    const float* diag     = (const float*)d_in[3];
    const float* feat     = (const float*)d_in[4];
    const float* W1       = (const float*)d_in[5];
    const float* b1       = (const float*)d_in[6];
    const float* W2       = (const float*)d_in[7];
    const float* b2       = (const float*)d_in[8];
    float* out = (float*)d_out;

    const int E = in_sizes[0];
    const int N = in_sizes[3];

    // workspace layout
    char* ws = (char*)d_ws;
    size_t off = 0;
    int* rp            = (int*)(ws + off);      off += (((size_t)(N + 1) * 4) + 255) & ~(size_t)255;
    uint32* featq      = (uint32*)(ws + off);   off += (size_t)N * (DD / 4) * 4;   // fp8 x
    uint32* interq     = (uint32*)(ws + off);   off += (size_t)N * (DD / 4) * 4;   // fp8 inter
    uint32* L1xbf      = (uint32*)(ws + off);   off += (size_t)N * (DD / 2) * 4;
    uint32* Linterbf   = (uint32*)(ws + off);   off += (size_t)N * (DD / 2) * 4;
    uint32* Wb1g       = (uint32*)(ws + off);   off += (size_t)DD * (DD / 2) * 4;
    uint32* Wb2g       = (uint32*)(ws + off);   off += (size_t)DD * (DD / 2) * 4;
    (void)ws_size; (void)n_in; (void)out_size;

    // 1. row_ptr
    k_row_ptr<<<(N + 1 + 255) / 256, 256, 0, stream>>>(edge_row, rp, N, E);
    // 2. prep: feat -> fp8, W -> bf16
    {
        int work = N * (DD / 4);
        if (work < 2 * DD * DD / 4) work = 2 * DD * DD / 4;
        k_prep<<<(work + 255) / 256, 256, 0, stream>>>(feat, featq, W1, W2, Wb1g, Wb2g, N);
    }
    // 3. SpMM pass 1: L1x (bf16), inter (fp8)
    k_spmm<1><<<(N + 3) / 4, 256, 0, stream>>>(edge_col, edge_val, (const ushort_t*)featq, rp,
                                               feat, diag, L1xbf, (ushort_t*)interq, N);
    // 4. SpMM pass 2: Linter (bf16)
    k_spmm<2><<<(N + 3) / 4, 256, 0, stream>>>(edge_col, edge_val, (const ushort_t*)interq, rp,
                                               nullptr, nullptr, Linterbf, nullptr, N);
    // 5. fused dual GEMM + bias (MFMA)
    k_gemm<<<(N + 255) / 256, 512, 0, stream>>>(L1xbf, Linterbf, Wb1g, Wb2g, b1, b2, out, N);
}